// Round 1
// baseline (133.004 us; speedup 1.0000x reference)
//
#include <hip/hip_runtime.h>

// x [B=16, N=1024, F=256] fp32.  Algebra (alpha folded away):
//   Wab = Wa^T @ Wb  (prep, bf16)          Wcb = bf16(Wr@Wu); bc = Wr@bu
//   ab  = x @ Wab^T   (proj)               U2 = x @ Wcb^T + bc
//   d[m] = x[m]·ab[m] (diag term; == alpha[m]·beta[m])
//   G[b][j][f] = sum_i U2[b,i,j] * ab[b,i,f]      (F x F per batch, K3 NT)
//   out[m,j] = (x[m,:]·G[b][j,:] - d[m]*U2[m,j]) / N + x[m,j]   (K4 NT)
// K2 proj2: {U2 natural} + {abT,U2T transposed} + dpart; packed b128 stores
// K3 m2   : G = U2T @ abT^T (NT, K=1024, BK=64), packed stores
// K4 final: out fp32, A-operand = x fp32 converted inline

typedef __bf16 bf16;
typedef float floatx4 __attribute__((ext_vector_type(4)));
typedef bf16 bf16x8 __attribute__((ext_vector_type(8)));
typedef bf16 bf16x4 __attribute__((ext_vector_type(4)));

constexpr int FD = 256;
constexpr int NB = 16;
constexpr int NN = 1024;
constexpr int RR = NB * NN;   // 16384

__device__ __forceinline__ bf16x8 cvt8(float4 a, float4 b) {
    bf16x8 o = { (bf16)a.x, (bf16)a.y, (bf16)a.z, (bf16)a.w,
                 (bf16)b.x, (bf16)b.y, (bf16)b.z, (bf16)b.w };
    return o;
}

// ---------------- K1: prep ----------------
__global__ __launch_bounds__(256)
void prep(const float* __restrict__ Wa, const float* __restrict__ Wb,
          const float* __restrict__ Wu, const float* __restrict__ bu,
          const float* __restrict__ Wr,
          bf16* __restrict__ Wcb, bf16* __restrict__ Wab, float* __restrict__ bc)
{
    const int blk = blockIdx.x, tid = threadIdx.x;
    if (blk < 256) {  // Wcb[j][f] = sum_g Wr[j][g]*Wu[g][f]; one j per block
        const int j = blk;
        float acc = 0.0f;
        for (int g = 0; g < FD; g += 4) {
            float4 wr = *(const float4*)&Wr[j * FD + g];
            acc += wr.x * Wu[g * FD + tid] + wr.y * Wu[(g + 1) * FD + tid]
                 + wr.z * Wu[(g + 2) * FD + tid] + wr.w * Wu[(g + 3) * FD + tid];
        }
        Wcb[j * FD + tid] = (bf16)acc;
    } else if (blk == 256) {  // bc[j] = Wr[j,:].bu
        float s = 0.0f;
        for (int g = 0; g < FD; g++) s += Wr[tid * FD + g] * bu[g];
        bc[tid] = s;
    } else {  // Wab[f][g] = sum_k Wa[k][f]*Wb[k][g]; one f per block
        const int f = blk - 257;
        float acc = 0.0f;
        for (int k = 0; k < FD; k += 4) {
            acc += Wa[k * FD + f] * Wb[k * FD + tid]
                 + Wa[(k + 1) * FD + f] * Wb[(k + 1) * FD + tid]
                 + Wa[(k + 2) * FD + f] * Wb[(k + 2) * FD + tid]
                 + Wa[(k + 3) * FD + f] * Wb[(k + 3) * FD + tid];
        }
        Wab[f * FD + tid] = (bf16)acc;
    }
}

// ---------------- K2: proj2 ----------------
__global__ __launch_bounds__(256)
void proj2(const float* __restrict__ x,
           const bf16* __restrict__ Wab, const bf16* __restrict__ Wc,
           bf16* __restrict__ U2, bf16* __restrict__ abT, bf16* __restrict__ U2T,
           const float* __restrict__ bc, float* __restrict__ dpart)
{
    constexpr int BM = 128, BN = 64, BK = 32, LDK = 36;
    __shared__ bf16 As[BM][LDK];
    __shared__ bf16 Bs[2][BN][LDK];
    __shared__ bf16 Tr[8960];   // union: natural [128][68] (8704) / transposed [64][140] (8960)
    const int tid = threadIdx.x;
    const int wave = tid >> 6, lane = tid & 63;
    const int q = lane >> 4, l16 = lane & 15;
    const int bm = blockIdx.y * BM, bn = blockIdx.x * BN;

    const int rowA0 = tid >> 2,          k8A0 = (tid & 3) * 8;
    const int rowA1 = (tid + 256) >> 2,  k8A1 = (tid & 3) * 8;
    const int rowW  = tid >> 2,          k8W  = (tid & 3) * 8;

    bf16x8 pxa0, pxa1; int4 pwq, pwc;
#define PROJ_LOAD(KK) do { \
        const float* s0 = &x[(size_t)(bm + rowA0) * FD + (KK) + k8A0]; \
        pxa0 = cvt8(*(const float4*)s0, *(const float4*)(s0 + 4)); \
        const float* s1 = &x[(size_t)(bm + rowA1) * FD + (KK) + k8A1]; \
        pxa1 = cvt8(*(const float4*)s1, *(const float4*)(s1 + 4)); \
        pwq = *(const int4*)&Wab[(size_t)(bn + rowW) * FD + (KK) + k8W]; \
        pwc = *(const int4*)&Wc[(size_t)(bn + rowW) * FD + (KK) + k8W]; \
    } while (0)

    floatx4 acc[2][2][4] = {};   // [0]=ab, [1]=U2
    PROJ_LOAD(0);

    for (int k0 = 0; k0 < FD; k0 += BK) {
        *(bf16x8*)&As[rowA0][k8A0] = pxa0;
        *(bf16x8*)&As[rowA1][k8A1] = pxa1;
        *(int4*)&Bs[0][rowW][k8W] = pwq;
        *(int4*)&Bs[1][rowW][k8W] = pwc;
        __syncthreads();
        if (k0 + BK < FD) PROJ_LOAD(k0 + BK);
        bf16x8 af[2];
        #pragma unroll
        for (int mi = 0; mi < 2; mi++)
            af[mi] = *(const bf16x8*)&As[wave * 32 + mi * 16 + l16][q * 8];
        #pragma unroll
        for (int w = 0; w < 2; w++) {
            bf16x8 bq[4];
            #pragma unroll
            for (int nj = 0; nj < 4; nj++)
                bq[nj] = *(const bf16x8*)&Bs[w][nj * 16 + l16][q * 8];
            #pragma unroll
            for (int mi = 0; mi < 2; mi++)
                #pragma unroll
                for (int nj = 0; nj < 4; nj++)
                    acc[w][mi][nj] = __builtin_amdgcn_mfma_f32_16x16x32_bf16(af[mi], bq[nj], acc[w][mi][nj], 0, 0, 0);
        }
        __syncthreads();
    }
#undef PROJ_LOAD

    const int b = bm >> 10, n0 = bm & (NN - 1);
    float bcv[4];
    #pragma unroll
    for (int nj = 0; nj < 4; nj++) bcv[nj] = bc[bn + nj * 16 + l16];

    // diag partials: d[m] (this block's 64 f-cols) = sum_f x[m,f]*ab[m,f]
    #pragma unroll
    for (int mi = 0; mi < 2; mi++)
        #pragma unroll
        for (int i = 0; i < 4; i++) {
            const int m = bm + wave * 32 + mi * 16 + q * 4 + i;
            float p = 0.0f;
            #pragma unroll
            for (int nj = 0; nj < 4; nj++)
                p += x[(size_t)m * FD + bn + nj * 16 + l16] * acc[0][mi][nj][i];
            #pragma unroll
            for (int off = 1; off < 16; off <<= 1) p += __shfl_xor(p, off);
            if (l16 == 0) dpart[(size_t)blockIdx.x * RR + m] = p;
        }

    // natural output via [128][68] repack: U2 (+bc)
    __syncthreads();
    #pragma unroll
    for (int mi = 0; mi < 2; mi++)
        #pragma unroll
        for (int i = 0; i < 4; i++) {
            int ml = wave * 32 + mi * 16 + q * 4 + i;
            #pragma unroll
            for (int nj = 0; nj < 4; nj++)
                Tr[ml * 68 + nj * 16 + l16] = (bf16)(acc[1][mi][nj][i] + bcv[nj]);
        }
    __syncthreads();
    #pragma unroll
    for (int it = 0; it < 4; it++) {
        int c = tid + it * 256;
        int row = c >> 3, chunk = c & 7;
        bf16x8 v = *(const bf16x8*)&Tr[row * 68 + chunk * 8];
        *(bf16x8*)&U2[(size_t)(bm + row) * FD + bn + chunk * 8] = v;
    }

    // transposed outputs via [64][140] repack: abT (pass 0), U2T (pass 1, +bc)
    #pragma unroll
    for (int pass = 0; pass < 2; pass++) {
        __syncthreads();
        #pragma unroll
        for (int mi = 0; mi < 2; mi++)
            #pragma unroll
            for (int nj = 0; nj < 4; nj++) {
                bf16x4 v4;
                #pragma unroll
                for (int i = 0; i < 4; i++) {
                    float v = acc[pass][mi][nj][i];
                    if (pass == 1) v += bcv[nj];
                    v4[i] = (bf16)v;
                }
                *(bf16x4*)&Tr[(nj * 16 + l16) * 140 + wave * 32 + mi * 16 + q * 4] = v4;
            }
        __syncthreads();
        bf16* dst = (pass ? U2T : abT) + (size_t)b * FD * NN;
        #pragma unroll
        for (int it = 0; it < 4; it++) {
            int c = tid + it * 256;
            int row = c >> 4, chunk = c & 15;
            bf16x8 v = *(const bf16x8*)&Tr[row * 140 + chunk * 8];
            *(bf16x8*)&dst[(size_t)(bn + row) * NN + n0 + chunk * 8] = v;
        }
    }
}

// ---------------- K3: G[b][j][f] = sum_n U2T[b][j][n] * abT[b][f][n] (BK=64) ----------------
__global__ __launch_bounds__(256)
void m2_mfma(const bf16* __restrict__ U2T, const bf16* __restrict__ abT, bf16* __restrict__ G)
{
    constexpr int LDK = 72;
    __shared__ bf16 As[64][LDK];
    __shared__ bf16 Bs[64][LDK];
    __shared__ bf16 Tr[64 * 68];
    const int tid = threadIdx.x;
    const int wave = tid >> 6, lane = tid & 63;
    const int q = lane >> 4, l16 = lane & 15;
    const int wj = wave >> 1, wk = wave & 1;
    const int b = blockIdx.z;
    const int bj = blockIdx.y * 64, bk = blockIdx.x * 64;
    const int r0 = tid >> 3,         k80 = (tid & 7) * 8;
    const int r1 = (tid + 256) >> 3, k81 = (tid & 7) * 8;
    const bf16* Arow0 = U2T + (size_t)b * FD * NN + (size_t)(bj + r0) * NN + k80;
    const bf16* Arow1 = U2T + (size_t)b * FD * NN + (size_t)(bj + r1) * NN + k81;
    const bf16* Brow0 = abT + (size_t)b * FD * NN + (size_t)(bk + r0) * NN + k80;
    const bf16* Brow1 = abT + (size_t)b * FD * NN + (size_t)(bk + r1) * NN + k81;

    int4 ra0 = *(const int4*)&Arow0[0];
    int4 ra1 = *(const int4*)&Arow1[0];
    int4 rb0 = *(const int4*)&Brow0[0];
    int4 rb1 = *(const int4*)&Brow1[0];
    floatx4 acc[2][2] = {};
    for (int n0 = 0; n0 < NN; n0 += 64) {
        *(int4*)&As[r0][k80] = ra0;
        *(int4*)&As[r1][k81] = ra1;
        *(int4*)&Bs[r0][k80] = rb0;
        *(int4*)&Bs[r1][k81] = rb1;
        __syncthreads();
        if (n0 + 64 < NN) {
            ra0 = *(const int4*)&Arow0[n0 + 64];
            ra1 = *(const int4*)&Arow1[n0 + 64];
            rb0 = *(const int4*)&Brow0[n0 + 64];
            rb1 = *(const int4*)&Brow1[n0 + 64];
        }
        #pragma unroll
        for (int kk = 0; kk < 2; kk++) {
            bf16x8 af[2], bq[2];
            #pragma unroll
            for (int mi = 0; mi < 2; mi++)
                af[mi] = *(const bf16x8*)&As[wj * 32 + mi * 16 + l16][kk * 32 + q * 8];
            #pragma unroll
            for (int kj = 0; kj < 2; kj++)
                bq[kj] = *(const bf16x8*)&Bs[wk * 32 + kj * 16 + l16][kk * 32 + q * 8];
            #pragma unroll
            for (int mi = 0; mi < 2; mi++)
                #pragma unroll
                for (int kj = 0; kj < 2; kj++)
                    acc[mi][kj] = __builtin_amdgcn_mfma_f32_16x16x32_bf16(af[mi], bq[kj], acc[mi][kj], 0, 0, 0);
        }
        __syncthreads();
    }
    // repack [64][68] then b128 stores
    __syncthreads();
    #pragma unroll
    for (int mi = 0; mi < 2; mi++)
        #pragma unroll
        for (int i = 0; i < 4; i++) {
            int jl = wj * 32 + mi * 16 + q * 4 + i;
            #pragma unroll
            for (int kj = 0; kj < 2; kj++)
                Tr[jl * 68 + wk * 32 + kj * 16 + l16] = (bf16)acc[mi][kj][i];
        }
    __syncthreads();
    bf16* Gb = G + (size_t)b * FD * FD;
    #pragma unroll
    for (int it = 0; it < 2; it++) {
        int c = tid + it * 256;
        int r = c >> 3, chunk = c & 7;
        bf16x8 v = *(const bf16x8*)&Tr[r * 68 + chunk * 8];
        *(bf16x8*)&Gb[(size_t)(bj + r) * FD + bk + chunk * 8] = v;
    }
}

// ---------------- K4: out = (x_bf @ G[b]^T(NT) - d*U2)/N + x ----------------
__global__ __launch_bounds__(256)
void final_mfma(const float* __restrict__ x, const bf16* __restrict__ G,
                const float* __restrict__ dpart, const bf16* __restrict__ U2,
                float* __restrict__ out)
{
    constexpr int BM = 128, BN = 64, BK = 32, LDK = 36;
    __shared__ bf16 As[BM][LDK];
    __shared__ bf16 Bs[BN][LDK];
    const int tid = threadIdx.x;
    const int wave = tid >> 6, lane = tid & 63;
    const int q = lane >> 4, l16 = lane & 15;
    const int bm = blockIdx.y * BM, bn = blockIdx.x * BN;
    const bf16* Gb = G + (size_t)(bm >> 10) * FD * FD;

    const int rowA0 = tid >> 2,         k8A0 = (tid & 3) * 8;
    const int rowA1 = (tid + 256) >> 2, k8A1 = (tid & 3) * 8;
    const int rowB  = tid >> 2,         k8B  = (tid & 3) * 8;

    bf16x8 ra0, ra1; int4 rb;
#define FIN_LOAD(KK) do { \
        const float* s0 = &x[(size_t)(bm + rowA0) * FD + (KK) + k8A0]; \
        ra0 = cvt8(*(const float4*)s0, *(const float4*)(s0 + 4)); \
        const float* s1 = &x[(size_t)(bm + rowA1) * FD + (KK) + k8A1]; \
        ra1 = cvt8(*(const float4*)s1, *(const float4*)(s1 + 4)); \
        rb = *(const int4*)&Gb[(size_t)(bn + rowB) * FD + (KK) + k8B]; \
    } while (0)

    floatx4 acc[2][4] = {};
    FIN_LOAD(0);
    for (int k0 = 0; k0 < FD; k0 += BK) {
        *(bf16x8*)&As[rowA0][k8A0] = ra0;
        *(bf16x8*)&As[rowA1][k8A1] = ra1;
        *(int4*)&Bs[rowB][k8B] = rb;
        __syncthreads();
        if (k0 + BK < FD) FIN_LOAD(k0 + BK);
        bf16x8 af[2], bq[4];
        #pragma unroll
        for (int mi = 0; mi < 2; mi++)
            af[mi] = *(const bf16x8*)&As[wave * 32 + mi * 16 + l16][q * 8];
        #pragma unroll
        for (int nj = 0; nj < 4; nj++)
            bq[nj] = *(const bf16x8*)&Bs[nj * 16 + l16][q * 8];
        #pragma unroll
        for (int mi = 0; mi < 2; mi++)
            #pragma unroll
            for (int nj = 0; nj < 4; nj++)
                acc[mi][nj] = __builtin_amdgcn_mfma_f32_16x16x32_bf16(af[mi], bq[nj], acc[mi][nj], 0, 0, 0);
        __syncthreads();
    }
#undef FIN_LOAD

    #pragma unroll
    for (int mi = 0; mi < 2; mi++)
        #pragma unroll
        for (int i = 0; i < 4; i++) {
            int m = bm + wave * 32 + mi * 16 + q * 4 + i;
            float d = dpart[m] + dpart[RR + m] + dpart[2 * RR + m] + dpart[3 * RR + m];
            #pragma unroll
            for (int nj = 0; nj < 4; nj++) {
                int n = bn + nj * 16 + l16;
                float v = (acc[mi][nj][i] - d * (float)U2[(size_t)m * FD + n]) * (1.0f / 1024.0f);
                out[(size_t)m * FD + n] = v + x[(size_t)m * FD + n];
            }
        }
}

extern "C" void kernel_launch(void* const* d_in, const int* in_sizes, int n_in,
                              void* d_out, int out_size, void* d_ws, size_t ws_size,
                              hipStream_t stream)
{
    const float* x  = (const float*)d_in[0];
    const float* Wa = (const float*)d_in[1];
    const float* Wb = (const float*)d_in[2];
    const float* Wu = (const float*)d_in[3];
    const float* bu = (const float*)d_in[4];
    const float* Wr = (const float*)d_in[5];
    float* out = (float*)d_out;

    char* w = (char*)d_ws;
    bf16* Wcb   = (bf16*)w;  w += (size_t)FD * FD * 2;
    bf16* Wab   = (bf16*)w;  w += (size_t)FD * FD * 2;
    float* bc   = (float*)w; w += (size_t)FD * 4;
    bf16* U2    = (bf16*)w;  w += (size_t)RR * FD * 2;
    bf16* abT   = (bf16*)w;  w += (size_t)RR * FD * 2;
    bf16* U2T   = (bf16*)w;  w += (size_t)RR * FD * 2;
    bf16* G     = (bf16*)w;  w += (size_t)NB * FD * FD * 2;
    float* dpart= (float*)w; w += (size_t)4 * RR * 4;

    dim3 blk(256);

    prep<<<dim3(513), blk, 0, stream>>>(Wa, Wb, Wu, bu, Wr, Wcb, Wab, bc);

    proj2<<<dim3(FD / 64, RR / 128), blk, 0, stream>>>(x, Wab, Wcb,
                                                       U2, abT, U2T, bc, dpart);

    m2_mfma<<<dim3(FD / 64, FD / 64, NB), blk, 0, stream>>>(U2T, abT, G);

    final_mfma<<<dim3(FD / 64, RR / 128), blk, 0, stream>>>(x, G, dpart, U2, out);
}